// Round 8
// baseline (755.516 us; speedup 1.0000x reference)
//
#include <hip/hip_runtime.h>
#include <stdint.h>

#define N_  32
#define C_  512
#define T_  2048
#define NB  1024
#define NT  (N_ * T_)          // 65536
#define GB_S 129               // gather buffer stride (+1 pad)

typedef _Float16 h8 __attribute__((ext_vector_type(8)));
typedef _Float16 h4 __attribute__((ext_vector_type(4)));
typedef float    f4 __attribute__((ext_vector_type(4)));

// ws byte offsets
#define WS_COMMIT   0
#define WS_SUMSQ    8
#define WS_COUNTS   64
#define WS_CNORM    4224
#define WS_RMIN     8320
#define WS_CBH      532608
#define WS_CBL      1581184
#define WS_XTH      2629760
#define WS_XTL      69738624
#define WS_NEED     136847488ull
#define WS_PCNT     136847488ull           // 256 panel counters (fast path only)
#define WS_NEED2    136848512ull

__device__ __forceinline__ void gll16(const void* g, void* l) {
    __builtin_amdgcn_global_load_lds((const __attribute__((address_space(1))) void*)g,
                                     (__attribute__((address_space(3))) void*)l, 16, 0, 0);
}

// ================= fused pre+xt: xt transpose/split (bid<8192) + cvt_cb/codenorm/init =================
__global__ __launch_bounds__(256)
void k_prext(const float* __restrict__ x, const float* __restrict__ cb,
             _Float16* __restrict__ xth, _Float16* __restrict__ xtl,
             float* __restrict__ sumsq, float* __restrict__ cnorm,
             _Float16* __restrict__ cbh, _Float16* __restrict__ cbl,
             unsigned* __restrict__ ws32, unsigned* __restrict__ pcnt,
             unsigned long long* __restrict__ rmin) {
    __shared__ float Ls[64 * 68];
    __shared__ float sred[4];
    const int bx = blockIdx.x;
    const int tid = threadIdx.x;

    if (bx >= 8192) {
        const int pid = bx - 8192;                    // pre-pass roles
        if (pid < 512) {
            int t = pid * 256 + tid;                  // 131072 threads x4 elems
            float4 v = *(const float4*)&cb[(size_t)t * 4];
            h4 hi, lo;
            hi.x = (_Float16)v.x; lo.x = (_Float16)(v.x - (float)hi.x);
            hi.y = (_Float16)v.y; lo.y = (_Float16)(v.y - (float)hi.y);
            hi.z = (_Float16)v.z; lo.z = (_Float16)(v.z - (float)hi.z);
            hi.w = (_Float16)v.w; lo.w = (_Float16)(v.w - (float)hi.w);
            *(h4*)&cbh[(size_t)t * 4] = hi;
            *(h4*)&cbl[(size_t)t * 4] = lo;
        } else if (pid < 516) {
            int j = (pid - 512) * 256 + tid;          // 1024 codebook rows
            const float* r = cb + (size_t)j * C_;
            float s = 0.f;
            for (int i = 0; i < C_; i += 4) {
                float4 v = *(const float4*)&r[i];
                s = fmaf(v.x, v.x, s); s = fmaf(v.y, v.y, s);
                s = fmaf(v.z, v.z, s); s = fmaf(v.w, v.w, s);
            }
            cnorm[j] = s;
        } else if (pid == 516) {
            for (int g = tid; g < 1040; g += 256) ws32[g] = 0u;   // commit+sumsq+counts
            if (tid < 256) pcnt[tid] = 0u;                         // panel counters
        } else {
            int g = (pid - 517) * 256 + tid;          // 65536 rmin entries
            rmin[g] = 0xFFFFFFFFFFFFFFFFull;
        }
        return;
    }

    // ---- xt role: x (n,c,t) -> xt[(n t)][c] f16 hi/lo split + total sum(x^2) ----
    const int n = bx >> 8;
    const int cblk = (bx >> 5) & 7, tblk = bx & 31;
    const int c0 = cblk * 64, t0 = tblk * 64;
    #pragma unroll
    for (int ld = 0; ld < 4; ++ld) {
        int idx = tid + ld * 256;
        int cc = idx >> 4, t4 = (idx & 15) << 2;
        float4 v = *(const float4*)&x[((size_t)n * C_ + c0 + cc) * T_ + t0 + t4];
        *(float4*)&Ls[cc * 68 + t4] = v;
    }
    __syncthreads();
    const int tt = tid >> 2, cs = (tid & 3) * 16;
    h8 hi0, hi1, lo0, lo1;
    float ss = 0.f;
    #pragma unroll
    for (int j = 0; j < 8; ++j) {
        float f = Ls[(cs + j) * 68 + tt];
        ss = fmaf(f, f, ss);
        _Float16 h = (_Float16)f;
        hi0[j] = h; lo0[j] = (_Float16)(f - (float)h);
    }
    #pragma unroll
    for (int j = 0; j < 8; ++j) {
        float f = Ls[(cs + 8 + j) * 68 + tt];
        ss = fmaf(f, f, ss);
        _Float16 h = (_Float16)f;
        hi1[j] = h; lo1[j] = (_Float16)(f - (float)h);
    }
    const size_t dst = ((size_t)n * T_ + t0 + tt) * C_ + c0 + cs;
    *(h8*)&xth[dst] = hi0; *(h8*)&xth[dst + 8] = hi1;
    *(h8*)&xtl[dst] = lo0; *(h8*)&xtl[dst + 8] = lo1;
    #pragma unroll
    for (int off = 32; off; off >>= 1) ss += __shfl_down(ss, off, 64);
    if ((tid & 63) == 0) sred[tid >> 6] = ss;
    __syncthreads();
    if (tid == 0) atomicAdd(sumsq, sred[0] + sred[1] + sred[2] + sred[3]);
}

// ---------------- standalone pre-pass kernels (middle-tier path) ----------------
__global__ __launch_bounds__(256)
void k_pre(const float* __restrict__ cb, float* __restrict__ cnorm,
           _Float16* __restrict__ cbh, _Float16* __restrict__ cbl,
           unsigned* __restrict__ ws32, unsigned long long* __restrict__ rmin) {
    const int bid = blockIdx.x, tid = threadIdx.x;
    if (bid < 512) {
        int t = bid * 256 + tid;
        float4 v = *(const float4*)&cb[(size_t)t * 4];
        h4 hi, lo;
        hi.x = (_Float16)v.x; lo.x = (_Float16)(v.x - (float)hi.x);
        hi.y = (_Float16)v.y; lo.y = (_Float16)(v.y - (float)hi.y);
        hi.z = (_Float16)v.z; lo.z = (_Float16)(v.z - (float)hi.z);
        hi.w = (_Float16)v.w; lo.w = (_Float16)(v.w - (float)hi.w);
        *(h4*)&cbh[(size_t)t * 4] = hi;
        *(h4*)&cbl[(size_t)t * 4] = lo;
    } else if (bid < 516) {
        int j = (bid - 512) * 256 + tid;
        const float* r = cb + (size_t)j * C_;
        float s = 0.f;
        for (int i = 0; i < C_; i += 4) {
            float4 v = *(const float4*)&r[i];
            s = fmaf(v.x, v.x, s); s = fmaf(v.y, v.y, s);
            s = fmaf(v.z, v.z, s); s = fmaf(v.w, v.w, s);
        }
        cnorm[j] = s;
    } else if (bid == 516) {
        for (int g = tid; g < 1040; g += 256) ws32[g] = 0u;
    } else {
        int g = (bid - 517) * 256 + tid;
        rmin[g] = 0xFFFFFFFFFFFFFFFFull;
    }
}

__global__ __launch_bounds__(256)
void k_xt(const float* __restrict__ x,
          _Float16* __restrict__ xth, _Float16* __restrict__ xtl,
          float* __restrict__ sumsq) {
    __shared__ float Ls[64 * 68];
    __shared__ float sred[4];
    const int bx = blockIdx.x;
    const int n = bx >> 8;
    const int cblk = (bx >> 5) & 7, tblk = bx & 31;
    const int c0 = cblk * 64, t0 = tblk * 64;
    const int tid = threadIdx.x;
    #pragma unroll
    for (int ld = 0; ld < 4; ++ld) {
        int idx = tid + ld * 256;
        int cc = idx >> 4, t4 = (idx & 15) << 2;
        float4 v = *(const float4*)&x[((size_t)n * C_ + c0 + cc) * T_ + t0 + t4];
        *(float4*)&Ls[cc * 68 + t4] = v;
    }
    __syncthreads();
    const int tt = tid >> 2, cs = (tid & 3) * 16;
    h8 hi0, hi1, lo0, lo1;
    float ss = 0.f;
    #pragma unroll
    for (int j = 0; j < 8; ++j) {
        float f = Ls[(cs + j) * 68 + tt];
        ss = fmaf(f, f, ss);
        _Float16 h = (_Float16)f;
        hi0[j] = h; lo0[j] = (_Float16)(f - (float)h);
    }
    #pragma unroll
    for (int j = 0; j < 8; ++j) {
        float f = Ls[(cs + 8 + j) * 68 + tt];
        ss = fmaf(f, f, ss);
        _Float16 h = (_Float16)f;
        hi1[j] = h; lo1[j] = (_Float16)(f - (float)h);
    }
    const size_t dst = ((size_t)n * T_ + t0 + tt) * C_ + c0 + cs;
    *(h8*)&xth[dst] = hi0; *(h8*)&xth[dst + 8] = hi1;
    *(h8*)&xtl[dst] = lo0; *(h8*)&xtl[dst + 8] = lo1;
    #pragma unroll
    for (int off = 32; off; off >>= 1) ss += __shfl_down(ss, off, 64);
    if ((tid & 63) == 0) sred[tid >> 6] = ss;
    __syncthreads();
    if (tid == 0) atomicAdd(sumsq, sred[0] + sred[1] + sred[2] + sred[3]);
}

// ---------------- MFMA GEMM + streaming argmin + (optional) last-arriver epilogue ----------------
// Inner loop = R5 verbatim (211us proven): 256x256 block tile, 512 threads, 8 waves,
// wave tile 64x128, 2x64KB LDS dbuf, zero-conflict swizzle, STAGE;COMPUTE;vmcnt(0);barrier.
// New: after argmin, blocks increment a per-panel counter; the 4th (last) block for a
// panel runs the k_post body for its 256 rows (two 128-row halves on 512 threads),
// overlapped with other blocks' GEMM work. rmin read back via atomic fetch (coherent).
__global__ __launch_bounds__(512, 2)
void k_gemm(const _Float16* __restrict__ xth, const _Float16* __restrict__ xtl,
            const _Float16* __restrict__ cbh, const _Float16* __restrict__ cbl,
            const float* __restrict__ cnorm, unsigned long long* __restrict__ rmin,
            const float* __restrict__ cb, float* __restrict__ out,
            float* __restrict__ commitAcc, int* __restrict__ counts,
            unsigned* __restrict__ pcnt, const int doEp) {
    __shared__ __attribute__((aligned(128))) char smc[131072];  // 2 x {Ah,Al,Bh,Bl}[256][32]
    __shared__ int sidx2[2][128];
    __shared__ float red2[2][4];
    __shared__ int sWin;

    const int tid = threadIdx.x;
    const int l = tid & 63, w = tid >> 6;
    const int q = l >> 4, r = l & 15;

    const int bid = blockIdx.x;                 // grid 1024
    const int swz = (bid & 7) * 128 + (bid >> 3);   // XCD-contiguous
    const int mb = swz >> 2, nb = swz & 3;      // 256 row-panels x 4 code-chunks

    const char* xthc = (const char*)xth;
    const char* xtlc = (const char*)xtl;
    const char* cbhc = (const char*)cbh;
    const char* cblc = (const char*)cbl;

    // ---- staging addressing (per wave: one stream, one 128-row half; 8 calls/tile) ----
    const int g16 = l >> 2;
    const int sslot = ((l & 3) ^ ((l >> 3) & 3)) << 4;   // inverse-swizzled source slot
    const int s = w >> 1;                             // 0 Ah, 1 Al, 2 Bh, 3 Bl
    const int rhalf = (w & 1) * 128;
    const char* sbase = (s == 0) ? xthc : (s == 1) ? xtlc : (s == 2) ? cbhc : cblc;
    const int rowblk = (s < 2) ? (mb * 256) : (nb * 256);
    const size_t srcOff = ((size_t)(rowblk + rhalf + g16)) * 1024 + sslot;
    const int ldsOff = s * 16384 + rhalf * 64;

    // ---- fragment read addressing (swizzled: slot = q ^ ((r>>1)&3)) ----
    const int wmi = w & 3, wni = w >> 2;              // 4 M-groups x 2 N-groups
    const int slq = (q ^ ((r >> 1) & 3)) << 4;
    const int aoffb = (wmi * 64 + r) * 64 + slq;          // Ah @ 0 (Al +16384)
    const int boffb = 32768 + (wni * 128 + r) * 64 + slq; // Bh @ 32768 (Bl +16384)

    f4 acc[4][8];
    #pragma unroll
    for (int i = 0; i < 4; ++i)
        #pragma unroll
        for (int j = 0; j < 8; ++j) acc[i][j] = (f4){0.f, 0.f, 0.f, 0.f};

#define STAGE_T(tt, bb) { \
    const char* sp_ = sbase + srcOff + (tt) * 64; \
    char* dp_ = smc + (bb) + ldsOff; \
    _Pragma("unroll") \
    for (int c_ = 0; c_ < 8; ++c_) gll16(sp_ + c_ * 16384, dp_ + c_ * 1024); }

    STAGE_T(0, 0);
    asm volatile("s_waitcnt vmcnt(0)" ::: "memory");
    __builtin_amdgcn_s_barrier();

    int b0 = 0;
    #pragma unroll 2
    for (int t = 0; t < 16; ++t) {
        if (t < 15) STAGE_T(t + 1, b0 ^ 65536);   // prefetch next tile into other buffer
        h8 ah[4], al[4];
        #pragma unroll
        for (int mf = 0; mf < 4; ++mf) {
            ah[mf] = *(const h8*)(smc + b0 + aoffb + mf * 1024);
            al[mf] = *(const h8*)(smc + b0 + 16384 + aoffb + mf * 1024);
        }
        __builtin_amdgcn_s_setprio(1);
        #pragma unroll
        for (int nf = 0; nf < 8; ++nf) {
            h8 bhf = *(const h8*)(smc + b0 + boffb + nf * 1024);
            h8 blf = *(const h8*)(smc + b0 + 16384 + boffb + nf * 1024);
            #pragma unroll
            for (int mf = 0; mf < 4; ++mf) {
                acc[mf][nf] = __builtin_amdgcn_mfma_f32_16x16x32_f16(ah[mf], bhf, acc[mf][nf], 0, 0, 0);
                acc[mf][nf] = __builtin_amdgcn_mfma_f32_16x16x32_f16(al[mf], bhf, acc[mf][nf], 0, 0, 0);
                acc[mf][nf] = __builtin_amdgcn_mfma_f32_16x16x32_f16(ah[mf], blf, acc[mf][nf], 0, 0, 0);
            }
        }
        __builtin_amdgcn_s_setprio(0);
        if (t < 15) {
            asm volatile("s_waitcnt vmcnt(0)" ::: "memory");
            __builtin_amdgcn_s_barrier();
            b0 ^= 65536;
        }
    }
#undef STAGE_T

    // streaming argmin epilogue: score = ||k||^2 - 2*dot
    const int codeBase = nb * 256 + wni * 128;
    const int rowBase  = mb * 256 + wmi * 64;
    float cn[8];
    #pragma unroll
    for (int nf = 0; nf < 8; ++nf) cn[nf] = cnorm[codeBase + nf * 16 + r];

    #pragma unroll
    for (int mf = 0; mf < 4; ++mf) {
        #pragma unroll
        for (int rg = 0; rg < 4; ++rg) {
            unsigned long long best = 0xFFFFFFFFFFFFFFFFull;
            #pragma unroll
            for (int nf = 0; nf < 8; ++nf) {
                float sc = fmaf(-2.0f, acc[mf][nf][rg], cn[nf]);
                unsigned u = __float_as_uint(sc);
                u = (u & 0x80000000u) ? ~u : (u | 0x80000000u);
                unsigned long long key =
                    ((unsigned long long)u << 32) | (unsigned)(codeBase + nf * 16 + r);
                best = key < best ? key : best;
            }
            #pragma unroll
            for (int off = 1; off < 16; off <<= 1) {
                unsigned long long o = __shfl_xor(best, off, 64);
                best = o < best ? o : best;
            }
            if (r == 0)
                atomicMin(&rmin[rowBase + mf * 16 + q * 4 + rg], best);
        }
    }

    if (!doEp) return;

    // ---------------- last-arriver epilogue (k_post body for this 256-row panel) ----------------
    __threadfence();
    __syncthreads();
    if (tid == 0) {
        unsigned old = atomicAdd(&pcnt[mb], 1u);
        sWin = (old == 3u);
    }
    __syncthreads();
    if (!sWin) return;

    const int sub = tid >> 8;            // two 128-row halves
    const int t2  = tid & 255;
    const size_t r0 = (size_t)mb * 256 + (size_t)sub * 128;
    const int n  = (int)(r0 >> 11);
    const int t0 = (int)(r0 & 2047);
    const size_t xbase = (size_t)n * C_ * T_ + t0;
    float* gbuf = (float*)smc + (size_t)sub * (64 * GB_S);

    float sc = 0.f;
    if (t2 < 128) {
        unsigned long long key = atomicAdd(&rmin[r0 + t2], 0ull);   // coherent fetch
        int code = (int)(key & 0xFFFFFFFFull);
        sidx2[sub][t2] = code;
        atomicAdd(&counts[code], 1);
        unsigned up = (unsigned)(key >> 32);
        unsigned ub = (up & 0x80000000u) ? (up & 0x7FFFFFFFu) : ~up;
        sc = __uint_as_float(ub);                                   // ||k||^2 - 2<x,k>
    }
    #pragma unroll
    for (int off = 32; off; off >>= 1) sc += __shfl_down(sc, off, 64);
    if ((t2 & 63) == 0) red2[sub][t2 >> 6] = sc;
    __syncthreads();
    if (t2 == 0) atomicAdd(commitAcc, red2[sub][0] + red2[sub][1] + red2[sub][2] + red2[sub][3]);

    const int tl   = t2 >> 1;
    const int half = t2 & 1;
    const int tcol  = t2 & 127;
    const int chalf = t2 >> 7;

    for (int c0 = 0; c0 < C_; c0 += 64) {
        __syncthreads();
        const int code = sidx2[sub][tl];
        const float* src = &cb[(size_t)code * C_ + c0 + half * 32];
        #pragma unroll
        for (int qq = 0; qq < 8; ++qq) {
            float4 v = *(const float4*)&src[qq * 4];
            const int cc = half * 32 + qq * 4;
            gbuf[(cc + 0) * GB_S + tl] = v.x;
            gbuf[(cc + 1) * GB_S + tl] = v.y;
            gbuf[(cc + 2) * GB_S + tl] = v.z;
            gbuf[(cc + 3) * GB_S + tl] = v.w;
        }
        __syncthreads();
        #pragma unroll 8
        for (int i = 0; i < 32; ++i) {
            const int cc = i * 2 + chalf;
            const size_t gidx = xbase + (size_t)(c0 + cc) * T_ + tcol;
            out[gidx] = gbuf[cc * GB_S + tcol];
        }
    }
}

// ---------------- standalone epilogue (middle-tier path) ----------------
__global__ __launch_bounds__(256)
void k_post(const float* __restrict__ cb,
            const unsigned long long* __restrict__ rmin,
            float* __restrict__ out, float* __restrict__ commitAcc,
            int* __restrict__ counts) {
    __shared__ float gbuf[64 * GB_S];
    __shared__ int sidx[128];
    __shared__ float red[4];
    const int bid = blockIdx.x;              // grid 512
    const int tid = threadIdx.x;
    const size_t r0 = (size_t)bid * 128;
    const int n  = (int)(r0 >> 11);
    const int t0 = (int)(r0 & 2047);
    const size_t xbase = (size_t)n * C_ * T_ + t0;

    float sc = 0.f;
    if (tid < 128) {
        unsigned long long key = rmin[r0 + tid];
        int code = (int)(key & 0xFFFFFFFFull);
        sidx[tid] = code;
        atomicAdd(&counts[code], 1);
        unsigned up = (unsigned)(key >> 32);
        unsigned ub = (up & 0x80000000u) ? (up & 0x7FFFFFFFu) : ~up;
        sc = __uint_as_float(ub);
    }
    #pragma unroll
    for (int off = 32; off; off >>= 1) sc += __shfl_down(sc, off, 64);
    if ((tid & 63) == 0) red[tid >> 6] = sc;
    __syncthreads();
    if (tid == 0) atomicAdd(commitAcc, red[0] + red[1] + red[2] + red[3]);

    const int tl   = tid >> 1;
    const int half = tid & 1;
    const int tcol  = tid & 127;
    const int chalf = tid >> 7;

    for (int c0 = 0; c0 < C_; c0 += 64) {
        __syncthreads();
        const int code = sidx[tl];
        const float* src = &cb[(size_t)code * C_ + c0 + half * 32];
        #pragma unroll
        for (int qq = 0; qq < 8; ++qq) {
            float4 v = *(const float4*)&src[qq * 4];
            const int cc = half * 32 + qq * 4;
            gbuf[(cc + 0) * GB_S + tl] = v.x;
            gbuf[(cc + 1) * GB_S + tl] = v.y;
            gbuf[(cc + 2) * GB_S + tl] = v.z;
            gbuf[(cc + 3) * GB_S + tl] = v.w;
        }
        __syncthreads();
        #pragma unroll 8
        for (int i = 0; i < 32; ++i) {
            const int cc = i * 2 + chalf;
            const size_t gidx = xbase + (size_t)(c0 + cc) * T_ + tcol;
            out[gidx] = gbuf[cc * GB_S + tcol];
        }
    }
}

// ---------------- finalize: perplexity + commit scalars ----------------
__global__ void k_final(const int* __restrict__ counts,
                        const float* __restrict__ commitAcc,
                        const float* __restrict__ sumsq,
                        float* __restrict__ out) {
    __shared__ float red[4];
    int tid = threadIdx.x;
    float s = 0.f;
    for (int j = tid; j < NB; j += 256) {
        float p = (float)counts[j] * (1.0f / (float)NT);
        s += p * logf(p + 1e-7f);
    }
    #pragma unroll
    for (int off = 32; off; off >>= 1) s += __shfl_down(s, off, 64);
    if ((tid & 63) == 0) red[tid >> 6] = s;
    __syncthreads();
    if (tid == 0) {
        float H = red[0] + red[1] + red[2] + red[3];
        out[(size_t)NT * C_]     = (commitAcc[0] + sumsq[0]) * (1.0f / ((float)NT * (float)C_));
        out[(size_t)NT * C_ + 1] = expf(-H);
    }
}

// ================= fallback fp32 path (proven, R1) =================
#define BM  128
#define BN  128
#define BK  16
#define AS_S 128
#define BS_S 132

__global__ __launch_bounds__(256, 4)
void k_main_fb(const float* __restrict__ x, const float* __restrict__ cb,
               const float* __restrict__ cnorm, float* __restrict__ out,
               float* __restrict__ commitAcc, int* __restrict__ counts) {
    __shared__ float smem[8256];
    __shared__ unsigned long long rmin[BM];
    __shared__ int sidx[BM];
    __shared__ float red[4];

    float* As = smem;
    float* Bs = smem + BK * AS_S;

    const int bid = blockIdx.x;
    const int n   = bid >> 4;
    const int t0  = (bid & 15) << 7;
    const int tid = threadIdx.x;
    const int tx  = tid & 15;
    const int ty  = tid >> 4;

    if (tid < BM) rmin[tid] = 0xFFFFFFFFFFFFFFFFull;

    const size_t xbase = (size_t)n * C_ * T_ + t0;

    for (int ch = 0; ch < NB / BN; ++ch) {
        const int j0 = ch * BN;
        float acc[2][2][4][4];
        #pragma unroll
        for (int a0 = 0; a0 < 2; ++a0)
            #pragma unroll
            for (int a1 = 0; a1 < 2; ++a1)
                #pragma unroll
                for (int a2 = 0; a2 < 4; ++a2)
                    #pragma unroll
                    for (int a3 = 0; a3 < 4; ++a3) acc[a0][a1][a2][a3] = 0.f;

        for (int kb = 0; kb < C_ / BK; ++kb) {
            const int k0 = kb * BK;
            __syncthreads();
            {
                const int kk = tid >> 5;
                const int m4 = (tid & 31) << 2;
                float4 a0v = *(const float4*)&x[xbase + (size_t)(k0 + kk) * T_ + m4];
                float4 a1v = *(const float4*)&x[xbase + (size_t)(k0 + kk + 8) * T_ + m4];
                *(float4*)&As[kk * AS_S + m4] = a0v;
                *(float4*)&As[(kk + 8) * AS_S + m4] = a1v;
                const int j  = tid >> 2;
                const int kq = (tid & 3) << 2;
                float4 b0v = *(const float4*)&cb[(size_t)(j0 + j) * C_ + k0 + kq];
                float4 b1v = *(const float4*)&cb[(size_t)(j0 + j + 64) * C_ + k0 + kq];
                Bs[(kq + 0) * BS_S + j] = b0v.x;
                Bs[(kq + 1) * BS_S + j] = b0v.y;
                Bs[(kq + 2) * BS_S + j] = b0v.z;
                Bs[(kq + 3) * BS_S + j] = b0v.w;
                Bs[(kq + 0) * BS_S + j + 64] = b1v.x;
                Bs[(kq + 1) * BS_S + j + 64] = b1v.y;
                Bs[(kq + 2) * BS_S + j + 64] = b1v.z;
                Bs[(kq + 3) * BS_S + j + 64] = b1v.w;
            }
            __syncthreads();
            #pragma unroll
            for (int kk = 0; kk < BK; ++kk) {
                float4 aL = *(const float4*)&As[kk * AS_S + (ty << 2)];
                float4 aH = *(const float4*)&As[kk * AS_S + 64 + (ty << 2)];
                float4 bL = *(const float4*)&Bs[kk * BS_S + (tx << 2)];
                float4 bH = *(const float4*)&Bs[kk * BS_S + 64 + (tx << 2)];
                float av[2][4] = {{aL.x, aL.y, aL.z, aL.w}, {aH.x, aH.y, aH.z, aH.w}};
                float bv[2][4] = {{bL.x, bL.y, bL.z, bL.w}, {bH.x, bH.y, bH.z, bH.w}};
                #pragma unroll
                for (int ih = 0; ih < 2; ++ih)
                    #pragma unroll
                    for (int i = 0; i < 4; ++i)
                        #pragma unroll
                        for (int jh = 0; jh < 2; ++jh)
                            #pragma unroll
                            for (int j = 0; j < 4; ++j)
                                acc[ih][jh][i][j] = fmaf(av[ih][i], bv[jh][j], acc[ih][jh][i][j]);
            }
        }

        float cnj[2][4];
        #pragma unroll
        for (int jh = 0; jh < 2; ++jh)
            #pragma unroll
            for (int j = 0; j < 4; ++j)
                cnj[jh][j] = cnorm[j0 + jh * 64 + (tx << 2) + j];

        #pragma unroll
        for (int ih = 0; ih < 2; ++ih) {
            #pragma unroll
            for (int i = 0; i < 4; ++i) {
                const int row = ih * 64 + (ty << 2) + i;
                unsigned long long best = 0xFFFFFFFFFFFFFFFFull;
                #pragma unroll
                for (int jh = 0; jh < 2; ++jh) {
                    #pragma unroll
                    for (int j = 0; j < 4; ++j) {
                        const int code = j0 + jh * 64 + (tx << 2) + j;
                        float s = fmaf(-2.0f, acc[ih][jh][i][j], cnj[jh][j]);
                        unsigned u = __float_as_uint(s);
                        u = (u & 0x80000000u) ? ~u : (u | 0x80000000u);
                        unsigned long long key =
                            ((unsigned long long)u << 32) | (unsigned)code;
                        best = key < best ? key : best;
                    }
                }
                #pragma unroll
                for (int off = 8; off; off >>= 1) {
                    unsigned long long o = __shfl_down(best, off, 16);
                    best = o < best ? o : best;
                }
                if (tx == 0) {
                    unsigned long long cur = rmin[row];
                    rmin[row] = best < cur ? best : cur;
                }
            }
        }
    }

    __syncthreads();
    if (tid < BM) {
        int code = (int)(rmin[tid] & 0xFFFFFFFFull);
        sidx[tid] = code;
        atomicAdd(&counts[code], 1);
    }
    __syncthreads();

    float* gbuf = smem;
    const int tl   = tid >> 1;
    const int half = tid & 1;
    const int tcol  = tid & 127;
    const int chalf = tid >> 7;
    float commit = 0.f;

    for (int c0 = 0; c0 < C_; c0 += 64) {
        __syncthreads();
        const int code = sidx[tl];
        const float* src = &cb[(size_t)code * C_ + c0 + half * 32];
        #pragma unroll
        for (int qq = 0; qq < 8; ++qq) {
            float4 v = *(const float4*)&src[qq * 4];
            const int cc = half * 32 + qq * 4;
            gbuf[(cc + 0) * GB_S + tl] = v.x;
            gbuf[(cc + 1) * GB_S + tl] = v.y;
            gbuf[(cc + 2) * GB_S + tl] = v.z;
            gbuf[(cc + 3) * GB_S + tl] = v.w;
        }
        __syncthreads();
        #pragma unroll 8
        for (int i = 0; i < 32; ++i) {
            const int cc = i * 2 + chalf;
            const size_t gidx = xbase + (size_t)(c0 + cc) * T_ + tcol;
            float g  = gbuf[cc * GB_S + tcol];
            float xv = x[gidx];
            out[gidx] = g;
            float d = xv - g;
            commit = fmaf(d, d, commit);
        }
    }

    #pragma unroll
    for (int off = 32; off; off >>= 1) commit += __shfl_down(commit, off, 64);
    if ((tid & 63) == 0) red[tid >> 6] = commit;
    __syncthreads();
    if (tid == 0) atomicAdd(commitAcc, red[0] + red[1] + red[2] + red[3]);
}

extern "C" void kernel_launch(void* const* d_in, const int* in_sizes, int n_in,
                              void* d_out, int out_size, void* d_ws, size_t ws_size,
                              hipStream_t stream) {
    const float* x  = (const float*)d_in[0];   // (32, 512, 2048)
    const float* cb = (const float*)d_in[1];   // (1024, 512)
    float* out = (float*)d_out;

    char* ws = (char*)d_ws;
    float* commitAcc = (float*)(ws + WS_COMMIT);
    float* sumsq     = (float*)(ws + WS_SUMSQ);
    int*   counts    = (int*)(ws + WS_COUNTS);
    float* cnorm     = (float*)(ws + WS_CNORM);
    unsigned long long* rmin = (unsigned long long*)(ws + WS_RMIN);
    _Float16* cbh = (_Float16*)(ws + WS_CBH);
    _Float16* cbl = (_Float16*)(ws + WS_CBL);
    _Float16* xth = (_Float16*)(ws + WS_XTH);
    _Float16* xtl = (_Float16*)(ws + WS_XTL);
    unsigned* pcnt = (unsigned*)(ws + WS_PCNT);

    if (ws_size >= WS_NEED2) {
        // 3-launch pipeline: fused pre+xt, fused gemm+epilogue, final
        k_prext<<<8965, 256, 0, stream>>>(x, cb, xth, xtl, sumsq, cnorm, cbh, cbl,
                                          (unsigned*)ws, pcnt, rmin);
        k_gemm<<<1024, 512, 0, stream>>>(xth, xtl, cbh, cbl, cnorm, rmin,
                                         cb, out, commitAcc, counts, pcnt, 1);
        k_final<<<1, 256, 0, stream>>>(counts, commitAcc, sumsq, out);
    } else if (ws_size >= WS_NEED) {
        // proven R5 5-launch pipeline
        k_pre<<<773, 256, 0, stream>>>(cb, cnorm, cbh, cbl, (unsigned*)ws, rmin);
        k_xt<<<8192, 256, 0, stream>>>(x, xth, xtl, sumsq);
        k_gemm<<<1024, 512, 0, stream>>>(xth, xtl, cbh, cbl, cnorm, rmin,
                                         cb, out, commitAcc, counts, (unsigned*)ws, 0);
        k_post<<<512, 256, 0, stream>>>(cb, rmin, out, commitAcc, counts);
        k_final<<<1, 256, 0, stream>>>(counts, commitAcc, sumsq, out);
    } else {
        __global__ void k_initS_decl();  // (unused forward decl appeasement)
        // fallback fp32 path
        // zero scalars+counts
        // reuse k_pre's init block is not available here; small dedicated launches:
        hipMemsetAsync(ws, 0, 4160, stream);   // commit+sumsq+counts
        k_codenorm_launch:
        {
            // codenorm via k_pre's middle role equivalent
        }
        k_pre<<<773, 256, 0, stream>>>(cb, cnorm, cbh, cbl, (unsigned*)ws, rmin);
        k_main_fb<<<512, 256, 0, stream>>>(x, cb, cnorm, out, commitAcc, counts);
        k_final<<<1, 256, 0, stream>>>(counts, commitAcc, sumsq, out);
    }
}

// Round 9
// 517.204 us; speedup vs baseline: 1.4608x; 1.4608x over previous
//
#include <hip/hip_runtime.h>
#include <stdint.h>

#define N_  32
#define C_  512
#define T_  2048
#define NB  1024
#define NT  (N_ * T_)          // 65536
#define GB_S 129               // gather buffer stride (+1 pad)

typedef _Float16 h8 __attribute__((ext_vector_type(8)));
typedef _Float16 h4 __attribute__((ext_vector_type(4)));
typedef float    f4 __attribute__((ext_vector_type(4)));

// ws byte offsets
#define WS_COMMIT   0
#define WS_SUMSQ    8
#define WS_COUNTS   64
#define WS_CNORM    4224
#define WS_RMIN     8320
#define WS_CBH      532608
#define WS_CBL      1581184
#define WS_XTH      2629760
#define WS_XTL      69738624
#define WS_NEED     136847488ull

__device__ __forceinline__ void gll16(const void* g, void* l) {
    __builtin_amdgcn_global_load_lds((const __attribute__((address_space(1))) void*)g,
                                     (__attribute__((address_space(3))) void*)l, 16, 0, 0);
}

// ================= fused pre+xt =================
// bx < 8192: x (n,c,t) -> xt[(n t)][c] f16 hi/lo split + sum(x^2).
//   LDS tile uses a 16-column ROTATION swizzle: value (row,col) stored at
//   col' = (col + 16*((row>>4)&3)) & 63.  Read banks: (4j + tt + {0,16,0,16})&31
//   -> exactly 2 lanes/bank (free), vs the old layout's 4-way conflict.
// bx >= 8192: pre roles (cvt_cb 512, codenorm 4, scalar init 1, rmin init 256).
__global__ __launch_bounds__(256)
void k_prext(const float* __restrict__ x, const float* __restrict__ cb,
             _Float16* __restrict__ xth, _Float16* __restrict__ xtl,
             float* __restrict__ sumsq, float* __restrict__ cnorm,
             _Float16* __restrict__ cbh, _Float16* __restrict__ cbl,
             unsigned* __restrict__ ws32, unsigned long long* __restrict__ rmin) {
    __shared__ float Ls[64 * 68];
    __shared__ float sred[4];
    const int bx = blockIdx.x;
    const int tid = threadIdx.x;

    if (bx >= 8192) {
        const int pid = bx - 8192;
        if (pid < 512) {
            int t = pid * 256 + tid;                  // 131072 threads x4 elems
            float4 v = *(const float4*)&cb[(size_t)t * 4];
            h4 hi, lo;
            hi.x = (_Float16)v.x; lo.x = (_Float16)(v.x - (float)hi.x);
            hi.y = (_Float16)v.y; lo.y = (_Float16)(v.y - (float)hi.y);
            hi.z = (_Float16)v.z; lo.z = (_Float16)(v.z - (float)hi.z);
            hi.w = (_Float16)v.w; lo.w = (_Float16)(v.w - (float)hi.w);
            *(h4*)&cbh[(size_t)t * 4] = hi;
            *(h4*)&cbl[(size_t)t * 4] = lo;
        } else if (pid < 516) {
            int j = (pid - 512) * 256 + tid;          // 1024 codebook rows
            const float* r = cb + (size_t)j * C_;
            float s = 0.f;
            for (int i = 0; i < C_; i += 4) {
                float4 v = *(const float4*)&r[i];
                s = fmaf(v.x, v.x, s); s = fmaf(v.y, v.y, s);
                s = fmaf(v.z, v.z, s); s = fmaf(v.w, v.w, s);
            }
            cnorm[j] = s;
        } else if (pid == 516) {
            for (int g = tid; g < 1040; g += 256) ws32[g] = 0u;   // commit+sumsq+counts
        } else {
            int g = (pid - 517) * 256 + tid;          // 65536 rmin entries
            rmin[g] = 0xFFFFFFFFFFFFFFFFull;
        }
        return;
    }

    // ---- xt role ----
    const int n = bx >> 8;
    const int cblk = (bx >> 5) & 7, tblk = bx & 31;
    const int c0 = cblk * 64, t0 = tblk * 64;
    #pragma unroll
    for (int ld = 0; ld < 4; ++ld) {
        int idx = tid + ld * 256;
        int cc = idx >> 4, t4 = (idx & 15) << 2;
        float4 v = *(const float4*)&x[((size_t)n * C_ + c0 + cc) * T_ + t0 + t4];
        const int rot = ((cc >> 4) & 3) << 4;
        *(float4*)&Ls[cc * 68 + ((t4 + rot) & 63)] = v;
    }
    __syncthreads();
    const int tt = tid >> 2, cs = (tid & 3) * 16;
    const int rrot = ((cs >> 4) & 3) << 4;            // row>>4 == cs>>4 for j<16
    const int ctt = (tt + rrot) & 63;                 // swizzled source column
    h8 hi0, hi1, lo0, lo1;
    float ss = 0.f;
    #pragma unroll
    for (int j = 0; j < 8; ++j) {
        float f = Ls[(cs + j) * 68 + ctt];
        ss = fmaf(f, f, ss);
        _Float16 h = (_Float16)f;
        hi0[j] = h; lo0[j] = (_Float16)(f - (float)h);
    }
    #pragma unroll
    for (int j = 0; j < 8; ++j) {
        float f = Ls[(cs + 8 + j) * 68 + ctt];
        ss = fmaf(f, f, ss);
        _Float16 h = (_Float16)f;
        hi1[j] = h; lo1[j] = (_Float16)(f - (float)h);
    }
    const size_t dst = ((size_t)n * T_ + t0 + tt) * C_ + c0 + cs;
    *(h8*)&xth[dst] = hi0; *(h8*)&xth[dst + 8] = hi1;
    *(h8*)&xtl[dst] = lo0; *(h8*)&xtl[dst + 8] = lo1;
    #pragma unroll
    for (int off = 32; off; off >>= 1) ss += __shfl_down(ss, off, 64);
    if ((tid & 63) == 0) sred[tid >> 6] = ss;
    __syncthreads();
    if (tid == 0) atomicAdd(sumsq, sred[0] + sred[1] + sred[2] + sred[3]);
}

// ---------------- init (fallback): zero commit+sumsq+counts only ----------------
__global__ void k_initS(unsigned* ws32) {
    int g = blockIdx.x * 256 + threadIdx.x;
    if (g < 1040) ws32[g] = 0u;
}

// ---------------- codebook row norms (fallback standalone) ----------------
__global__ void k_codenorm(const float* __restrict__ cb, float* __restrict__ cnorm) {
    int j = blockIdx.x * 256 + threadIdx.x;   // grid 4 -> 1024
    const float* r = cb + (size_t)j * C_;
    float s = 0.f;
    for (int i = 0; i < C_; i += 4) {
        float4 v = *(const float4*)&r[i];
        s = fmaf(v.x, v.x, s); s = fmaf(v.y, v.y, s);
        s = fmaf(v.z, v.z, s); s = fmaf(v.w, v.w, s);
    }
    cnorm[j] = s;
}

// ---------------- MFMA GEMM + streaming argmin (R5-exact, 211us proven) ----------------
// 256x256 block tile, 512 threads, 8 waves, wave tile 64x128, double-buffered
// 2x64KB LDS, 1-tile prefetch drained at vmcnt(0)+barrier, zero-conflict swizzle
// slot ^= (row>>1)&3 (R4/R5-proven: SQ_LDS_BANK_CONFLICT == 0).
__global__ __launch_bounds__(512, 2)
void k_gemm(const _Float16* __restrict__ xth, const _Float16* __restrict__ xtl,
            const _Float16* __restrict__ cbh, const _Float16* __restrict__ cbl,
            const float* __restrict__ cnorm, unsigned long long* __restrict__ rmin) {
    __shared__ __attribute__((aligned(128))) char smc[131072];  // 2 x {Ah,Al,Bh,Bl}[256][32]
    const int tid = threadIdx.x;
    const int l = tid & 63, w = tid >> 6;
    const int q = l >> 4, r = l & 15;

    const int bid = blockIdx.x;                 // grid 1024
    const int swz = (bid & 7) * 128 + (bid >> 3);   // XCD-contiguous
    const int mb = swz >> 2, nb = swz & 3;      // 256 row-panels x 4 code-chunks

    const char* xthc = (const char*)xth;
    const char* xtlc = (const char*)xtl;
    const char* cbhc = (const char*)cbh;
    const char* cblc = (const char*)cbl;

    // ---- staging addressing (per wave: one stream, one 128-row half; 8 calls/tile) ----
    const int g16 = l >> 2;                           // row within 16-row call group
    const int sslot = ((l & 3) ^ ((l >> 3) & 3)) << 4;   // inverse-swizzled source slot: p ^ ((row>>1)&3)
    const int s = w >> 1;                             // 0 Ah, 1 Al, 2 Bh, 3 Bl
    const int rhalf = (w & 1) * 128;
    const char* sbase = (s == 0) ? xthc : (s == 1) ? xtlc : (s == 2) ? cbhc : cblc;
    const int rowblk = (s < 2) ? (mb * 256) : (nb * 256);
    const size_t srcOff = ((size_t)(rowblk + rhalf + g16)) * 1024 + sslot;
    const int ldsOff = s * 16384 + rhalf * 64;

    // ---- fragment read addressing (swizzled: slot = q ^ ((r>>1)&3)) ----
    const int wmi = w & 3, wni = w >> 2;              // 4 M-groups x 2 N-groups
    const int slq = (q ^ ((r >> 1) & 3)) << 4;
    const int aoffb = (wmi * 64 + r) * 64 + slq;          // Ah @ 0 (Al +16384)
    const int boffb = 32768 + (wni * 128 + r) * 64 + slq; // Bh @ 32768 (Bl +16384)

    f4 acc[4][8];
    #pragma unroll
    for (int i = 0; i < 4; ++i)
        #pragma unroll
        for (int j = 0; j < 8; ++j) acc[i][j] = (f4){0.f, 0.f, 0.f, 0.f};

#define STAGE_T(tt, bb) { \
    const char* sp_ = sbase + srcOff + (tt) * 64; \
    char* dp_ = smc + (bb) + ldsOff; \
    _Pragma("unroll") \
    for (int c_ = 0; c_ < 8; ++c_) gll16(sp_ + c_ * 16384, dp_ + c_ * 1024); }

    STAGE_T(0, 0);
    asm volatile("s_waitcnt vmcnt(0)" ::: "memory");
    __builtin_amdgcn_s_barrier();

    int b0 = 0;
    #pragma unroll 2
    for (int t = 0; t < 16; ++t) {
        if (t < 15) STAGE_T(t + 1, b0 ^ 65536);   // prefetch next tile into other buffer
        h8 ah[4], al[4];
        #pragma unroll
        for (int mf = 0; mf < 4; ++mf) {
            ah[mf] = *(const h8*)(smc + b0 + aoffb + mf * 1024);
            al[mf] = *(const h8*)(smc + b0 + 16384 + aoffb + mf * 1024);
        }
        __builtin_amdgcn_s_setprio(1);
        #pragma unroll
        for (int nf = 0; nf < 8; ++nf) {
            h8 bhf = *(const h8*)(smc + b0 + boffb + nf * 1024);
            h8 blf = *(const h8*)(smc + b0 + 16384 + boffb + nf * 1024);
            #pragma unroll
            for (int mf = 0; mf < 4; ++mf) {
                acc[mf][nf] = __builtin_amdgcn_mfma_f32_16x16x32_f16(ah[mf], bhf, acc[mf][nf], 0, 0, 0);
                acc[mf][nf] = __builtin_amdgcn_mfma_f32_16x16x32_f16(al[mf], bhf, acc[mf][nf], 0, 0, 0);
                acc[mf][nf] = __builtin_amdgcn_mfma_f32_16x16x32_f16(ah[mf], blf, acc[mf][nf], 0, 0, 0);
            }
        }
        __builtin_amdgcn_s_setprio(0);
        if (t < 15) {
            asm volatile("s_waitcnt vmcnt(0)" ::: "memory");  // next tile landed (covered by MFMAs)
            __builtin_amdgcn_s_barrier();
            b0 ^= 65536;
        }
    }
#undef STAGE_T

    // streaming argmin epilogue: score = ||k||^2 - 2*dot
    const int codeBase = nb * 256 + wni * 128;
    const int rowBase  = mb * 256 + wmi * 64;
    float cn[8];
    #pragma unroll
    for (int nf = 0; nf < 8; ++nf) cn[nf] = cnorm[codeBase + nf * 16 + r];

    #pragma unroll
    for (int mf = 0; mf < 4; ++mf) {
        #pragma unroll
        for (int rg = 0; rg < 4; ++rg) {
            unsigned long long best = 0xFFFFFFFFFFFFFFFFull;
            #pragma unroll
            for (int nf = 0; nf < 8; ++nf) {
                float sc = fmaf(-2.0f, acc[mf][nf][rg], cn[nf]);
                unsigned u = __float_as_uint(sc);
                u = (u & 0x80000000u) ? ~u : (u | 0x80000000u);
                unsigned long long key =
                    ((unsigned long long)u << 32) | (unsigned)(codeBase + nf * 16 + r);
                best = key < best ? key : best;
            }
            #pragma unroll
            for (int off = 1; off < 16; off <<= 1) {
                unsigned long long o = __shfl_xor(best, off, 64);
                best = o < best ? o : best;
            }
            if (r == 0)
                atomicMin(&rmin[rowBase + mf * 16 + q * 4 + rg], best);
        }
    }
}

// ---------------- epilogue: gather + out + counts + commit (from decoded scores) ----------------
__global__ __launch_bounds__(256)
void k_post(const float* __restrict__ cb,
            const unsigned long long* __restrict__ rmin,
            float* __restrict__ out, float* __restrict__ commitAcc,
            int* __restrict__ counts) {
    __shared__ float gbuf[64 * GB_S];
    __shared__ int sidx[128];
    __shared__ float red[4];
    const int bid = blockIdx.x;              // grid 512
    const int tid = threadIdx.x;
    const size_t r0 = (size_t)bid * 128;
    const int n  = (int)(r0 >> 11);
    const int t0 = (int)(r0 & 2047);
    const size_t xbase = (size_t)n * C_ * T_ + t0;

    float sc = 0.f;
    if (tid < 128) {
        unsigned long long key = rmin[r0 + tid];
        int code = (int)(key & 0xFFFFFFFFull);
        sidx[tid] = code;
        atomicAdd(&counts[code], 1);
        unsigned up = (unsigned)(key >> 32);                 // decode monotonic key -> score
        unsigned ub = (up & 0x80000000u) ? (up & 0x7FFFFFFFu) : ~up;
        sc = __uint_as_float(ub);                            // ||k||^2 - 2<x,k>
    }
    #pragma unroll
    for (int off = 32; off; off >>= 1) sc += __shfl_down(sc, off, 64);
    if ((tid & 63) == 0) red[tid >> 6] = sc;
    __syncthreads();
    if (tid == 0) atomicAdd(commitAcc, red[0] + red[1] + red[2] + red[3]);

    const int tl   = tid >> 1;
    const int half = tid & 1;
    const int tcol  = tid & 127;
    const int chalf = tid >> 7;

    for (int c0 = 0; c0 < C_; c0 += 64) {
        __syncthreads();
        const int code = sidx[tl];
        const float* src = &cb[(size_t)code * C_ + c0 + half * 32];
        #pragma unroll
        for (int qq = 0; qq < 8; ++qq) {
            float4 v = *(const float4*)&src[qq * 4];
            const int cc = half * 32 + qq * 4;
            gbuf[(cc + 0) * GB_S + tl] = v.x;
            gbuf[(cc + 1) * GB_S + tl] = v.y;
            gbuf[(cc + 2) * GB_S + tl] = v.z;
            gbuf[(cc + 3) * GB_S + tl] = v.w;
        }
        __syncthreads();
        #pragma unroll 8
        for (int i = 0; i < 32; ++i) {
            const int cc = i * 2 + chalf;
            const size_t gidx = xbase + (size_t)(c0 + cc) * T_ + tcol;
            out[gidx] = gbuf[cc * GB_S + tcol];
        }
    }
}

// ---------------- finalize: perplexity + commit scalars ----------------
__global__ void k_final(const int* __restrict__ counts,
                        const float* __restrict__ commitAcc,
                        const float* __restrict__ sumsq,
                        float* __restrict__ out) {
    __shared__ float red[4];
    int tid = threadIdx.x;
    float s = 0.f;
    for (int j = tid; j < NB; j += 256) {
        float p = (float)counts[j] * (1.0f / (float)NT);
        s += p * logf(p + 1e-7f);
    }
    #pragma unroll
    for (int off = 32; off; off >>= 1) s += __shfl_down(s, off, 64);
    if ((tid & 63) == 0) red[tid >> 6] = s;
    __syncthreads();
    if (tid == 0) {
        float H = red[0] + red[1] + red[2] + red[3];
        out[(size_t)NT * C_]     = (commitAcc[0] + sumsq[0]) * (1.0f / ((float)NT * (float)C_));
        out[(size_t)NT * C_ + 1] = expf(-H);
    }
}

// ================= fallback fp32 path (proven, R1) =================
#define BM  128
#define BN  128
#define BK  16
#define AS_S 128
#define BS_S 132

__global__ __launch_bounds__(256, 4)
void k_main_fb(const float* __restrict__ x, const float* __restrict__ cb,
               const float* __restrict__ cnorm, float* __restrict__ out,
               float* __restrict__ commitAcc, int* __restrict__ counts) {
    __shared__ float smem[8256];
    __shared__ unsigned long long rmin[BM];
    __shared__ int sidx[BM];
    __shared__ float red[4];

    float* As = smem;
    float* Bs = smem + BK * AS_S;

    const int bid = blockIdx.x;
    const int n   = bid >> 4;
    const int t0  = (bid & 15) << 7;
    const int tid = threadIdx.x;
    const int tx  = tid & 15;
    const int ty  = tid >> 4;

    if (tid < BM) rmin[tid] = 0xFFFFFFFFFFFFFFFFull;

    const size_t xbase = (size_t)n * C_ * T_ + t0;

    for (int ch = 0; ch < NB / BN; ++ch) {
        const int j0 = ch * BN;
        float acc[2][2][4][4];
        #pragma unroll
        for (int a0 = 0; a0 < 2; ++a0)
            #pragma unroll
            for (int a1 = 0; a1 < 2; ++a1)
                #pragma unroll
                for (int a2 = 0; a2 < 4; ++a2)
                    #pragma unroll
                    for (int a3 = 0; a3 < 4; ++a3) acc[a0][a1][a2][a3] = 0.f;

        for (int kb = 0; kb < C_ / BK; ++kb) {
            const int k0 = kb * BK;
            __syncthreads();
            {
                const int kk = tid >> 5;
                const int m4 = (tid & 31) << 2;
                float4 a0v = *(const float4*)&x[xbase + (size_t)(k0 + kk) * T_ + m4];
                float4 a1v = *(const float4*)&x[xbase + (size_t)(k0 + kk + 8) * T_ + m4];
                *(float4*)&As[kk * AS_S + m4] = a0v;
                *(float4*)&As[(kk + 8) * AS_S + m4] = a1v;
                const int j  = tid >> 2;
                const int kq = (tid & 3) << 2;
                float4 b0v = *(const float4*)&cb[(size_t)(j0 + j) * C_ + k0 + kq];
                float4 b1v = *(const float4*)&cb[(size_t)(j0 + j + 64) * C_ + k0 + kq];
                Bs[(kq + 0) * BS_S + j] = b0v.x;
                Bs[(kq + 1) * BS_S + j] = b0v.y;
                Bs[(kq + 2) * BS_S + j] = b0v.z;
                Bs[(kq + 3) * BS_S + j] = b0v.w;
                Bs[(kq + 0) * BS_S + j + 64] = b1v.x;
                Bs[(kq + 1) * BS_S + j + 64] = b1v.y;
                Bs[(kq + 2) * BS_S + j + 64] = b1v.z;
                Bs[(kq + 3) * BS_S + j + 64] = b1v.w;
            }
            __syncthreads();
            #pragma unroll
            for (int kk = 0; kk < BK; ++kk) {
                float4 aL = *(const float4*)&As[kk * AS_S + (ty << 2)];
                float4 aH = *(const float4*)&As[kk * AS_S + 64 + (ty << 2)];
                float4 bL = *(const float4*)&Bs[kk * BS_S + (tx << 2)];
                float4 bH = *(const float4*)&Bs[kk * BS_S + 64 + (tx << 2)];
                float av[2][4] = {{aL.x, aL.y, aL.z, aL.w}, {aH.x, aH.y, aH.z, aH.w}};
                float bv[2][4] = {{bL.x, bL.y, bL.z, bL.w}, {bH.x, bH.y, bH.z, bH.w}};
                #pragma unroll
                for (int ih = 0; ih < 2; ++ih)
                    #pragma unroll
                    for (int i = 0; i < 4; ++i)
                        #pragma unroll
                        for (int jh = 0; jh < 2; ++jh)
                            #pragma unroll
                            for (int j = 0; j < 4; ++j)
                                acc[ih][jh][i][j] = fmaf(av[ih][i], bv[jh][j], acc[ih][jh][i][j]);
            }
        }

        float cnj[2][4];
        #pragma unroll
        for (int jh = 0; jh < 2; ++jh)
            #pragma unroll
            for (int j = 0; j < 4; ++j)
                cnj[jh][j] = cnorm[j0 + jh * 64 + (tx << 2) + j];

        #pragma unroll
        for (int ih = 0; ih < 2; ++ih) {
            #pragma unroll
            for (int i = 0; i < 4; ++i) {
                const int row = ih * 64 + (ty << 2) + i;
                unsigned long long best = 0xFFFFFFFFFFFFFFFFull;
                #pragma unroll
                for (int jh = 0; jh < 2; ++jh) {
                    #pragma unroll
                    for (int j = 0; j < 4; ++j) {
                        const int code = j0 + jh * 64 + (tx << 2) + j;
                        float s = fmaf(-2.0f, acc[ih][jh][i][j], cnj[jh][j]);
                        unsigned u = __float_as_uint(s);
                        u = (u & 0x80000000u) ? ~u : (u | 0x80000000u);
                        unsigned long long key =
                            ((unsigned long long)u << 32) | (unsigned)code;
                        best = key < best ? key : best;
                    }
                }
                #pragma unroll
                for (int off = 8; off; off >>= 1) {
                    unsigned long long o = __shfl_down(best, off, 16);
                    best = o < best ? o : best;
                }
                if (tx == 0) {
                    unsigned long long cur = rmin[row];
                    rmin[row] = best < cur ? best : cur;
                }
            }
        }
    }

    __syncthreads();
    if (tid < BM) {
        int code = (int)(rmin[tid] & 0xFFFFFFFFull);
        sidx[tid] = code;
        atomicAdd(&counts[code], 1);
    }
    __syncthreads();

    float* gbuf = smem;
    const int tl   = tid >> 1;
    const int half = tid & 1;
    const int tcol  = tid & 127;
    const int chalf = tid >> 7;
    float commit = 0.f;

    for (int c0 = 0; c0 < C_; c0 += 64) {
        __syncthreads();
        const int code = sidx[tl];
        const float* src = &cb[(size_t)code * C_ + c0 + half * 32];
        #pragma unroll
        for (int qq = 0; qq < 8; ++qq) {
            float4 v = *(const float4*)&src[qq * 4];
            const int cc = half * 32 + qq * 4;
            gbuf[(cc + 0) * GB_S + tl] = v.x;
            gbuf[(cc + 1) * GB_S + tl] = v.y;
            gbuf[(cc + 2) * GB_S + tl] = v.z;
            gbuf[(cc + 3) * GB_S + tl] = v.w;
        }
        __syncthreads();
        #pragma unroll 8
        for (int i = 0; i < 32; ++i) {
            const int cc = i * 2 + chalf;
            const size_t gidx = xbase + (size_t)(c0 + cc) * T_ + tcol;
            float g  = gbuf[cc * GB_S + tcol];
            float xv = x[gidx];
            out[gidx] = g;
            float d = xv - g;
            commit = fmaf(d, d, commit);
        }
    }

    #pragma unroll
    for (int off = 32; off; off >>= 1) commit += __shfl_down(commit, off, 64);
    if ((tid & 63) == 0) red[tid >> 6] = commit;
    __syncthreads();
    if (tid == 0) atomicAdd(commitAcc, red[0] + red[1] + red[2] + red[3]);
}

extern "C" void kernel_launch(void* const* d_in, const int* in_sizes, int n_in,
                              void* d_out, int out_size, void* d_ws, size_t ws_size,
                              hipStream_t stream) {
    const float* x  = (const float*)d_in[0];   // (32, 512, 2048)
    const float* cb = (const float*)d_in[1];   // (1024, 512)
    float* out = (float*)d_out;

    char* ws = (char*)d_ws;
    float* commitAcc = (float*)(ws + WS_COMMIT);
    float* sumsq     = (float*)(ws + WS_SUMSQ);
    int*   counts    = (int*)(ws + WS_COUNTS);
    float* cnorm     = (float*)(ws + WS_CNORM);
    unsigned long long* rmin = (unsigned long long*)(ws + WS_RMIN);
    _Float16* cbh = (_Float16*)(ws + WS_CBH);
    _Float16* cbl = (_Float16*)(ws + WS_CBL);
    _Float16* xth = (_Float16*)(ws + WS_XTH);
    _Float16* xtl = (_Float16*)(ws + WS_XTL);

    if (ws_size >= WS_NEED) {
        // 4-launch pipeline: fused pre+xt, gemm (R5-exact), post, final
        k_prext<<<8965, 256, 0, stream>>>(x, cb, xth, xtl, sumsq, cnorm, cbh, cbl,
                                          (unsigned*)ws, rmin);
        k_gemm<<<1024, 512, 0, stream>>>(xth, xtl, cbh, cbl, cnorm, rmin);
        k_post<<<512, 256, 0, stream>>>(cb, rmin, out, commitAcc, counts);
        k_final<<<1, 256, 0, stream>>>(counts, commitAcc, sumsq, out);
    } else {
        k_initS<<<5, 256, 0, stream>>>((unsigned*)ws);
        k_codenorm<<<4, 256, 0, stream>>>(cb, cnorm);
        k_main_fb<<<512, 256, 0, stream>>>(x, cb, cnorm, out, commitAcc, counts);
        k_final<<<1, 256, 0, stream>>>(counts, commitAcc, sumsq, out);
    }
}